// Round 1
// baseline (43.513 us; speedup 1.0000x reference)
//
#include <hip/hip_runtime.h>
#include <math.h>

// ---------------------------------------------------------------------------
// Problem constants (from reference)
// ---------------------------------------------------------------------------
#define IN_DIM   16
#define CD       7
#define SAMPS    20
#define KFILT    101
#define SIGLEN   140      // CD * SAMPS
#define MCONST   128      // 2^CD
static __device__ __constant__ double d_PI = 3.14159265358979323846;

// ws layout (bytes):
//   [0          .. 4096)   : double partials[512]
//   [4096       .. 4488)   : double G[49]
//   [4488       .. 4496)   : double norm
//   [4496       .. 5520)   : float  trig[256]  (cos[0..127], sin[0..127])

// ---------------------------------------------------------------------------
// Kernel B: per-row encoder, partial sum of squares (deterministic tree)
// ---------------------------------------------------------------------------
__global__ __launch_bounds__(256) void k_enc_partial(
    const float* __restrict__ x,
    const float* __restrict__ We1, const float* __restrict__ be1,
    const float* __restrict__ We2, const float* __restrict__ be2,
    double* __restrict__ partials, int B)
{
    __shared__ float sW1[256], sb1[16], sW2[112], sb2[7];
    __shared__ double red[256];
    int t = threadIdx.x;
    if (t < 256) sW1[t] = We1[t];
    if (t < 112) sW2[t] = We2[t];
    if (t < 16)  sb1[t] = be1[t];
    if (t < 7)   sb2[t] = be2[t];
    __syncthreads();

    int row = blockIdx.x * 256 + t;
    double ss = 0.0;
    if (row < B) {
        const float4* xp = reinterpret_cast<const float4*>(x + (size_t)row * IN_DIM);
        float4 v0 = xp[0], v1 = xp[1], v2 = xp[2], v3 = xp[3];
        float xr[16] = {v0.x,v0.y,v0.z,v0.w, v1.x,v1.y,v1.z,v1.w,
                        v2.x,v2.y,v2.z,v2.w, v3.x,v3.y,v3.z,v3.w};
        float h[16];
        #pragma unroll
        for (int i = 0; i < 16; ++i) {
            float acc = sb1[i];
            #pragma unroll
            for (int j = 0; j < 16; ++j) acc = fmaf(sW1[i*16+j], xr[j], acc);
            h[i] = (acc >= 0.f) ? acc : 0.01f * acc;
        }
        #pragma unroll
        for (int o = 0; o < 7; ++o) {
            float acc = sb2[o];
            #pragma unroll
            for (int i = 0; i < 16; ++i) acc = fmaf(sW2[o*16+i], h[i], acc);
            ss += (double)acc * (double)acc;
        }
    }
    red[t] = ss;
    __syncthreads();
    #pragma unroll
    for (int s = 128; s > 0; s >>= 1) {
        if (t < s) red[t] += red[t + s];
        __syncthreads();
    }
    if (t == 0) partials[blockIdx.x] = red[0];
}

// ---------------------------------------------------------------------------
// Kernel C (1 block, 1024 thr): reduce partials -> norm, trig table, G matrix
// ---------------------------------------------------------------------------
__global__ __launch_bounds__(1024) void k_prep(
    const double* __restrict__ partials, int NB,
    const float* __restrict__ h_lp, const float* __restrict__ h_ps,
    double* __restrict__ Gout, double* __restrict__ norm_out,
    float* __restrict__ trig)
{
    __shared__ double cur[CD][SIGLEN];
    __shared__ double nxt[CD][SIGLEN];
    __shared__ float  hps[KFILT], hlp[KFILT];
    __shared__ double red[512];
    int t = threadIdx.x;

    // ---- norm reduction (deterministic) ----
    if (t < 512) {
        double s = 0.0;
        for (int i = t; i < NB; i += 512) s += partials[i];
        red[t] = s;
    }
    __syncthreads();
    #pragma unroll
    for (int k = 256; k > 0; k >>= 1) {
        if (t < k) red[t] += red[t + k];
        __syncthreads();
    }
    if (t == 0) norm_out[0] = sqrt(red[0]);

    // ---- trig table: cos/sin(2*pi/128 * idx), matching f32 reference path ----
    if (t < MCONST) {
        float ph = (float)(2.0 * 3.14159265358979323846 / (double)MCONST) * (float)t;
        trig[t]          = cosf(ph);
        trig[MCONST + t] = sinf(ph);
    }

    // ---- G: push 7 basis vectors through the truncated 3-conv chain ----
    if (t < KFILT) { hps[t] = h_ps[t]; hlp[t] = h_lp[t]; }
    int b = t / SIGLEN;           // basis index (symbol position)
    int p = t - b * SIGLEN;       // signal position
    bool act = (t < CD * SIGLEN);
    if (act) cur[b][p] = (p == SAMPS * b) ? 1.0 : 0.0;
    __syncthreads();

    for (int f = 0; f < 3; ++f) {
        const float* h = (f == 1) ? hlp : hps;
        if (act) {
            double acc = 0.0;
            for (int m = 0; m < KFILT; ++m) {
                int j = p + 50 - m;            // out[n] = sum_m h[m]*in[n+50-m]
                double v = (j >= 0 && j < SIGLEN) ? cur[b][j] : 0.0;
                acc += (double)h[m] * v;
            }
            nxt[b][p] = acc;
        }
        __syncthreads();
        if (act) cur[b][p] = nxt[b][p];
        __syncthreads();
    }
    if (act && (p % SAMPS) == 0) {
        int k = p / SAMPS;
        Gout[k * CD + b] = (double)SAMPS * cur[b][p];   // y[k] = sum_c G[k,c] s[c]
    }
}

// ---------------------------------------------------------------------------
// Kernel D: full per-row pipeline
// ---------------------------------------------------------------------------
__global__ __launch_bounds__(256) void k_main(
    const float* __restrict__ x,
    const float* __restrict__ We1, const float* __restrict__ be1,
    const float* __restrict__ We2, const float* __restrict__ be2,
    const float* __restrict__ Wd1, const float* __restrict__ bd1,
    const float* __restrict__ Wd2, const float* __restrict__ bd2,
    const float* __restrict__ noise, const int* __restrict__ snr_p,
    const double* __restrict__ Gd, const double* __restrict__ norm_d,
    const float* __restrict__ trig,
    float* __restrict__ out, int B)
{
    __shared__ float sW1[256], sb1[16], sW2[112], sb2[7];
    __shared__ float sV1[112], sc1[16], sV2[256], sc2[16];
    __shared__ float str[2 * MCONST];
    __shared__ double sG[49];
    __shared__ float snorm, sdenom;
    int t = threadIdx.x;
    if (t < 256) { sW1[t] = We1[t]; sV2[t] = Wd2[t]; str[t] = trig[t]; }
    if (t < 112) { sW2[t] = We2[t]; sV1[t] = Wd1[t]; }
    if (t < 16)  { sb1[t] = be1[t]; sc1[t] = bd1[t]; sc2[t] = bd2[t]; }
    if (t < 7)   sb2[t] = be2[t];
    if (t < 49)  sG[t] = Gd[t];
    if (t == 0) {
        snorm = (float)norm_d[0];
        // snr may arrive as int32 or float32 single-element array
        int iv = *snr_p;
        float sv = (iv >= -1000 && iv <= 1000) ? (float)iv
                                               : *reinterpret_cast<const float*>(snr_p);
        float snr_lin = powf(10.0f, 0.1f * sv);
        sdenom = sqrtf((float)(8.0 / 7.0) * snr_lin);  // sqrt(2*rate*snr_lin), rate=4/7
    }
    __syncthreads();

    int row = blockIdx.x * 256 + t;
    if (row >= B) return;

    const float4* xp = reinterpret_cast<const float4*>(x + (size_t)row * IN_DIM);
    float4 v0 = xp[0], v1 = xp[1], v2 = xp[2], v3 = xp[3];
    float xr[16] = {v0.x,v0.y,v0.z,v0.w, v1.x,v1.y,v1.z,v1.w,
                    v2.x,v2.y,v2.z,v2.w, v3.x,v3.y,v3.z,v3.w};

    // encoder
    float h[16];
    #pragma unroll
    for (int i = 0; i < 16; ++i) {
        float acc = sb1[i];
        #pragma unroll
        for (int j = 0; j < 16; ++j) acc = fmaf(sW1[i*16+j], xr[j], acc);
        h[i] = (acc >= 0.f) ? acc : 0.01f * acc;
    }
    float sr[CD], si[CD], sgn[CD];
    #pragma unroll
    for (int o = 0; o < CD; ++o) {
        float acc = sb2[o];
        #pragma unroll
        for (int i = 0; i < 16; ++i) acc = fmaf(sW2[o*16+i], h[i], acc);
        float es = acc / snorm * 70.0f;          // enc / ||enc|| * 70
        float rv = rintf(es);                    // jnp.round = half-to-even
        int xi = (int)rv;
        sgn[o] = (xi < 0) ? -1.0f : 1.0f;
        int idx = (xi < 0 ? -xi : xi) & (MCONST - 1);   // mod(|xi|, 128)
        sr[o] = str[idx];
        si[o] = str[MCONST + idx];
    }

    // channel: y = G * s, demodulate
    float res[CD];
    #pragma unroll
    for (int k = 0; k < CD; ++k) {
        double yr = 0.0, yi = 0.0;
        #pragma unroll
        for (int c = 0; c < CD; ++c) {
            double g = sG[k * CD + c];
            yr += g * (double)sr[c];
            yi += g * (double)si[c];
        }
        float ang = atan2f((float)yi, (float)yr);
        float q = ang * (float)(128.0 / (2.0 * 3.14159265358979323846));
        float r = rintf(q);
        float m = fmodf(r, 128.0f);
        if (m < 0.0f) m += 128.0f;               // jnp.mod semantics
        res[k] = m * sgn[k] + noise[(size_t)row * CD + k] / sdenom;
    }

    // decoder
    float dd[16];
    #pragma unroll
    for (int i = 0; i < 16; ++i) {
        float acc = sc1[i];
        #pragma unroll
        for (int c = 0; c < CD; ++c) acc = fmaf(sV1[i*CD+c], res[c], acc);
        dd[i] = (acc >= 0.f) ? acc : 0.01f * acc;
    }
    float4* op = reinterpret_cast<float4*>(out + (size_t)row * IN_DIM);
    #pragma unroll
    for (int q4 = 0; q4 < 4; ++q4) {
        float o0[4];
        #pragma unroll
        for (int u = 0; u < 4; ++u) {
            int i = q4 * 4 + u;
            float acc = sc2[i];
            #pragma unroll
            for (int j = 0; j < 16; ++j) acc = fmaf(sV2[i*16+j], dd[j], acc);
            o0[u] = acc;
        }
        op[q4] = make_float4(o0[0], o0[1], o0[2], o0[3]);
    }
}

// ---------------------------------------------------------------------------
extern "C" void kernel_launch(void* const* d_in, const int* in_sizes, int n_in,
                              void* d_out, int out_size, void* d_ws, size_t ws_size,
                              hipStream_t stream)
{
    const float* x    = (const float*)d_in[0];
    const float* We1  = (const float*)d_in[1];
    const float* be1  = (const float*)d_in[2];
    const float* We2  = (const float*)d_in[3];
    const float* be2  = (const float*)d_in[4];
    const float* Wd1  = (const float*)d_in[5];
    const float* bd1  = (const float*)d_in[6];
    const float* Wd2  = (const float*)d_in[7];
    const float* bd2  = (const float*)d_in[8];
    const float* h_lp = (const float*)d_in[9];
    const float* h_ps = (const float*)d_in[10];
    const float* noise= (const float*)d_in[11];
    const int*   snr  = (const int*)d_in[12];
    float* out = (float*)d_out;

    int B  = in_sizes[0] / IN_DIM;
    int NB = (B + 255) / 256;   // 512 for B=131072

    char* ws = (char*)d_ws;
    double* partials = (double*)(ws + 0);
    double* Gd       = (double*)(ws + 4096);
    double* norm_d   = (double*)(ws + 4488);
    float*  trig     = (float*) (ws + 4496);

    k_enc_partial<<<NB, 256, 0, stream>>>(x, We1, be1, We2, be2, partials, B);
    k_prep<<<1, 1024, 0, stream>>>(partials, NB, h_lp, h_ps, Gd, norm_d, trig);
    k_main<<<NB, 256, 0, stream>>>(x, We1, be1, We2, be2, Wd1, bd1, Wd2, bd2,
                                   noise, snr, Gd, norm_d, trig, out, B);
}

// Round 2
// 34.226 us; speedup vs baseline: 1.2713x; 1.2713x over previous
//
#include <hip/hip_runtime.h>
#include <math.h>

// ---------------------------------------------------------------------------
// Problem constants (from reference)
// ---------------------------------------------------------------------------
#define IN_DIM   16
#define CD       7
#define SAMPS    20
#define KFILT    101
#define SIGLEN   140      // CD * SAMPS
#define MCONST   128      // 2^CD

// ws layout (bytes):
//   [0    .. 4096)  : double partials[512]
//   [4096 .. 4488)  : double G[49]
//   [4488 .. 4496)  : double norm
//   [4496 .. 5520)  : float  trig[256]  (cos[0..127], sin[0..127])
//   [8192 .. +4.2MB): float  enc[B][8]  (padded row of 7)

// ---------------------------------------------------------------------------
// Kernel B: per-row encoder -> enc staged to ws, partial sum of squares
// ---------------------------------------------------------------------------
__global__ __launch_bounds__(256) void k_enc_partial(
    const float* __restrict__ x,
    const float* __restrict__ We1, const float* __restrict__ be1,
    const float* __restrict__ We2, const float* __restrict__ be2,
    float* __restrict__ enc, double* __restrict__ partials, int B)
{
    __shared__ float sW1[256], sb1[16], sW2[112], sb2[7];
    __shared__ double red[256];
    int t = threadIdx.x;
    if (t < 256) sW1[t] = We1[t];
    if (t < 112) sW2[t] = We2[t];
    if (t < 16)  sb1[t] = be1[t];
    if (t < 7)   sb2[t] = be2[t];
    __syncthreads();

    int row = blockIdx.x * 256 + t;
    double ss = 0.0;
    if (row < B) {
        const float4* xp = reinterpret_cast<const float4*>(x + (size_t)row * IN_DIM);
        float4 v0 = xp[0], v1 = xp[1], v2 = xp[2], v3 = xp[3];
        float xr[16] = {v0.x,v0.y,v0.z,v0.w, v1.x,v1.y,v1.z,v1.w,
                        v2.x,v2.y,v2.z,v2.w, v3.x,v3.y,v3.z,v3.w};
        float h[16];
        #pragma unroll
        for (int i = 0; i < 16; ++i) {
            float acc = sb1[i];
            #pragma unroll
            for (int j = 0; j < 16; ++j) acc = fmaf(sW1[i*16+j], xr[j], acc);
            h[i] = (acc >= 0.f) ? acc : 0.01f * acc;
        }
        float e[8];
        #pragma unroll
        for (int o = 0; o < 7; ++o) {
            float acc = sb2[o];
            #pragma unroll
            for (int i = 0; i < 16; ++i) acc = fmaf(sW2[o*16+i], h[i], acc);
            e[o] = acc;
            ss += (double)acc * (double)acc;
        }
        e[7] = 0.f;
        float4* ep = reinterpret_cast<float4*>(enc + (size_t)row * 8);
        ep[0] = make_float4(e[0], e[1], e[2], e[3]);
        ep[1] = make_float4(e[4], e[5], e[6], e[7]);
    }
    red[t] = ss;
    __syncthreads();
    #pragma unroll
    for (int s = 128; s > 0; s >>= 1) {
        if (t < s) red[t] += red[t + s];
        __syncthreads();
    }
    if (t == 0) partials[blockIdx.x] = red[0];
}

// ---------------------------------------------------------------------------
// Kernel C (8 blocks x 256): blocks 0-6 -> one basis column of G each;
//                            block 7   -> norm reduction + trig table
// ---------------------------------------------------------------------------
__global__ __launch_bounds__(256) void k_prep(
    const double* __restrict__ partials, int NB,
    const float* __restrict__ h_lp, const float* __restrict__ h_ps,
    double* __restrict__ Gout, double* __restrict__ norm_out,
    float* __restrict__ trig)
{
    int t = threadIdx.x;
    int blk = blockIdx.x;

    if (blk == 7) {
        // ---- norm reduction (deterministic) ----
        __shared__ double red[256];
        double s = 0.0;
        for (int i = t; i < NB; i += 256) s += partials[i];
        red[t] = s;
        __syncthreads();
        #pragma unroll
        for (int k = 128; k > 0; k >>= 1) {
            if (t < k) red[t] += red[t + k];
            __syncthreads();
        }
        if (t == 0) norm_out[0] = sqrt(red[0]);
        // ---- trig table (f32, matches reference cos/sin path) ----
        if (t < MCONST) {
            float ph = (float)(2.0 * 3.14159265358979323846 / (double)MCONST) * (float)t;
            trig[t]          = cosf(ph);
            trig[MCONST + t] = sinf(ph);
        }
        return;
    }

    // ---- basis `blk`: delta at position 20*blk through 3 truncated convs ----
    __shared__ double cur[SIGLEN], nxt[SIGLEN];
    __shared__ float hps[KFILT], hlp[KFILT];
    if (t < KFILT) { hps[t] = h_ps[t]; hlp[t] = h_lp[t]; }
    __syncthreads();

    // stage 1: conv(delta_at(20*blk), h_ps) = shifted h_ps (with truncation)
    if (t < SIGLEN) {
        int m = t + 50 - SAMPS * blk;   // out[n] = h[n+50-pos]
        cur[t] = (m >= 0 && m < KFILT) ? (double)hps[m] : 0.0;
    }
    __syncthreads();

    // stages 2,3: full truncated convs
    for (int f = 0; f < 2; ++f) {
        const float* h = (f == 0) ? hlp : hps;
        if (t < SIGLEN) {
            double acc = 0.0;
            for (int m = 0; m < KFILT; ++m) {
                int j = t + 50 - m;
                if (j >= 0 && j < SIGLEN) acc += (double)h[m] * cur[j];
            }
            nxt[t] = acc;
        }
        __syncthreads();
        if (t < SIGLEN) cur[t] = nxt[t];
        __syncthreads();
    }
    if (t < CD) Gout[t * CD + blk] = (double)SAMPS * cur[t * SAMPS];
}

// ---------------------------------------------------------------------------
// Kernel D: modulation + channel + demod + noise + decoder
// ---------------------------------------------------------------------------
__global__ __launch_bounds__(256) void k_main(
    const float* __restrict__ enc,
    const float* __restrict__ Wd1, const float* __restrict__ bd1,
    const float* __restrict__ Wd2, const float* __restrict__ bd2,
    const float* __restrict__ noise, const int* __restrict__ snr_p,
    const double* __restrict__ Gd, const double* __restrict__ norm_d,
    const float* __restrict__ trig,
    float* __restrict__ out, int B)
{
    __shared__ float sV1[112], sc1[16], sV2[256], sc2[16];
    __shared__ float str[2 * MCONST];
    __shared__ double sG[49];
    __shared__ float snorm, sdenom;
    int t = threadIdx.x;
    if (t < 256) { sV2[t] = Wd2[t]; str[t] = trig[t]; }
    if (t < 112) sV1[t] = Wd1[t];
    if (t < 16)  { sc1[t] = bd1[t]; sc2[t] = bd2[t]; }
    if (t < 49)  sG[t] = Gd[t];
    if (t == 0) {
        snorm = (float)norm_d[0];
        int iv = *snr_p;
        float sv = (iv >= -1000 && iv <= 1000) ? (float)iv
                                               : *reinterpret_cast<const float*>(snr_p);
        float snr_lin = powf(10.0f, 0.1f * sv);
        sdenom = sqrtf((float)(8.0 / 7.0) * snr_lin);  // sqrt(2*rate*snr_lin), rate=4/7
    }
    __syncthreads();

    int row = blockIdx.x * 256 + t;
    if (row >= B) return;

    const float4* ep = reinterpret_cast<const float4*>(enc + (size_t)row * 8);
    float4 e0 = ep[0], e1 = ep[1];
    float ev[7] = {e0.x, e0.y, e0.z, e0.w, e1.x, e1.y, e1.z};

    float sr[CD], si[CD], sgn[CD];
    #pragma unroll
    for (int o = 0; o < CD; ++o) {
        float es = ev[o] / snorm * 70.0f;        // enc / ||enc|| * 70
        float rv = rintf(es);                    // jnp.round = half-to-even
        int xi = (int)rv;
        sgn[o] = (xi < 0) ? -1.0f : 1.0f;
        int idx = (xi < 0 ? -xi : xi) & (MCONST - 1);   // mod(|xi|, 128)
        sr[o] = str[idx];
        si[o] = str[MCONST + idx];
    }

    // channel: y = G * s, demodulate
    float res[CD];
    #pragma unroll
    for (int k = 0; k < CD; ++k) {
        double yr = 0.0, yi = 0.0;
        #pragma unroll
        for (int c = 0; c < CD; ++c) {
            double g = sG[k * CD + c];
            yr += g * (double)sr[c];
            yi += g * (double)si[c];
        }
        float ang = atan2f((float)yi, (float)yr);
        float q = ang * (float)(128.0 / (2.0 * 3.14159265358979323846));
        float r = rintf(q);
        float m = fmodf(r, 128.0f);
        if (m < 0.0f) m += 128.0f;               // jnp.mod semantics
        res[k] = m * sgn[k] + noise[(size_t)row * CD + k] / sdenom;
    }

    // decoder
    float dd[16];
    #pragma unroll
    for (int i = 0; i < 16; ++i) {
        float acc = sc1[i];
        #pragma unroll
        for (int c = 0; c < CD; ++c) acc = fmaf(sV1[i*CD+c], res[c], acc);
        dd[i] = (acc >= 0.f) ? acc : 0.01f * acc;
    }
    float4* op = reinterpret_cast<float4*>(out + (size_t)row * IN_DIM);
    #pragma unroll
    for (int q4 = 0; q4 < 4; ++q4) {
        float o0[4];
        #pragma unroll
        for (int u = 0; u < 4; ++u) {
            int i = q4 * 4 + u;
            float acc = sc2[i];
            #pragma unroll
            for (int j = 0; j < 16; ++j) acc = fmaf(sV2[i*16+j], dd[j], acc);
            o0[u] = acc;
        }
        op[q4] = make_float4(o0[0], o0[1], o0[2], o0[3]);
    }
}

// ---------------------------------------------------------------------------
extern "C" void kernel_launch(void* const* d_in, const int* in_sizes, int n_in,
                              void* d_out, int out_size, void* d_ws, size_t ws_size,
                              hipStream_t stream)
{
    const float* x    = (const float*)d_in[0];
    const float* We1  = (const float*)d_in[1];
    const float* be1  = (const float*)d_in[2];
    const float* We2  = (const float*)d_in[3];
    const float* be2  = (const float*)d_in[4];
    const float* Wd1  = (const float*)d_in[5];
    const float* bd1  = (const float*)d_in[6];
    const float* Wd2  = (const float*)d_in[7];
    const float* bd2  = (const float*)d_in[8];
    const float* h_lp = (const float*)d_in[9];
    const float* h_ps = (const float*)d_in[10];
    const float* noise= (const float*)d_in[11];
    const int*   snr  = (const int*)d_in[12];
    float* out = (float*)d_out;

    int B  = in_sizes[0] / IN_DIM;
    int NB = (B + 255) / 256;   // 512 for B=131072

    char* ws = (char*)d_ws;
    double* partials = (double*)(ws + 0);
    double* Gd       = (double*)(ws + 4096);
    double* norm_d   = (double*)(ws + 4488);
    float*  trig     = (float*) (ws + 4496);
    float*  enc      = (float*) (ws + 8192);

    k_enc_partial<<<NB, 256, 0, stream>>>(x, We1, be1, We2, be2, enc, partials, B);
    k_prep<<<8, 256, 0, stream>>>(partials, NB, h_lp, h_ps, Gd, norm_d, trig);
    k_main<<<NB, 256, 0, stream>>>(enc, Wd1, bd1, Wd2, bd2,
                                   noise, snr, Gd, norm_d, trig, out, B);
}